// Round 14
// baseline (284.732 us; speedup 1.0000x reference)
//
#include <hip/hip_runtime.h>
#include <hip/hip_bf16.h>

typedef __attribute__((ext_vector_type(4))) float f32x4;
typedef __attribute__((ext_vector_type(8))) short bf16x8;
typedef __attribute__((ext_vector_type(8))) unsigned short u16x8;
typedef __attribute__((ext_vector_type(4))) unsigned int u32x4;

#define IH 112
#define IW 112
#define CIN 64
#define COUT 128
#define HOUT 110
#define WOUT 110
#define MTOT 387200
#define NWGF 3520  // 32 * 110 blocks, one (b, ho) row each

__device__ __forceinline__ unsigned short f2bf(float f) {
  unsigned int x = __float_as_uint(f);
  x += 0x7fffu + ((x >> 16) & 1u);
  return (unsigned short)(x >> 16);
}

// packed fp32 pair -> bf16 pair (v_cvt_pk_bf16_f32)
__device__ __forceinline__ unsigned int cvt2(float lo, float hi) {
  union { __hip_bfloat162 h; unsigned int u; } cv;
  cv.h = __float22bfloat162_rn(float2{lo, hi});
  return cv.u;
}

// ---- prepack kernels (3,3,64,128) fp32 HWIO -> bt[tap][co][ci] bf16, LINEAR
// (B is consumed by per-lane global loads now -- no LDS image, no swizzle).
__global__ void prepack_b_kernel(const float* __restrict__ kern,
                                 unsigned short* __restrict__ bt) {
  int idx = blockIdx.x * 256 + threadIdx.x;
  if (idx >= 9 * 8192) return;
  int tap = idx >> 13;
  int rem = idx & 8191;
  int co = rem >> 6;
  int ci = rem & 63;
  bt[idx] = f2bf(kern[(tap * 64 + ci) * COUT + co]);
}

// ---- fused main: block = (b, ho). A-slab (3 rows x 112 px x 64 ch bf16,
// 43 KB) staged once (in-kernel fp32->bf16); B fragments loaded DIRECTLY from
// L2-resident bt (L1 serves the 4x m-wave re-reads). K-loop is BARRIER-FREE:
// no LDS writes after the slab stage -> waves run unsynchronized, latency
// self-covered by 16 waves/CU.
__global__ __launch_bounds__(512, 4)
void conv_fused_kernel(const float* __restrict__ x,
                       const unsigned short* __restrict__ bt,
                       const float* __restrict__ bias,
                       float* __restrict__ out) {
  __shared__ __align__(16) unsigned short Asl[336 * 64];  // 43008 B

  const int tid = threadIdx.x;
  const int lane = tid & 63;
  const int wid = tid >> 6;

  // XCD-chunked remap: 3520 % 8 == 0 -> simple chunking, 440 blocks/XCD.
  const int bid = blockIdx.x;
  const int wg = (bid & 7) * 440 + (bid >> 3);
  const int bb = wg / 110;
  const int ho = wg - bb * 110;

  // ---- stage A-slab (R13-proven): slab row u = kh*112 + p holds
  // x[bb, ho+kh, p, 0:64] bf16, chunks XOR-swizzled with key (u&7)==(p&7).
  {
    const float* xbase = x + ((size_t)(bb * IH + ho) * IW) * CIN;
    for (int it = tid; it < 672; it += 512) {
      const int u = it >> 1;        // slab row 0..335
      const int h = it & 1;         // half: channels h*32 .. h*32+31
      const int kh = u / 112;
      const int p = u - kh * 112;
      const float* src = xbase + (kh * IW + p) * CIN + h * 32;
      const int key = u & 7;
      unsigned short* rowp = Asl + u * 64;
#pragma unroll
      for (int c2 = 0; c2 < 4; ++c2) {
        f32x4 a = *(const f32x4*)(src + c2 * 8);
        f32x4 b = *(const f32x4*)(src + c2 * 8 + 4);
        u32x4 v;
        v[0] = cvt2(a[0], a[1]); v[1] = cvt2(a[2], a[3]);
        v[2] = cvt2(b[0], b[1]); v[3] = cvt2(b[2], b[3]);
        const int c = h * 4 + c2;
        *(u32x4*)(rowp + ((c ^ key) << 3)) = v;
      }
    }
  }
  __syncthreads();  // slab staged -- the ONLY barrier in this kernel

  // ---- compute config: 8 waves = 4(m) x 2(n); wave tile 32x64 = 2x4 frags
  const int wm = wid >> 1;
  const int wn = wid & 1;
  const int l16 = lane & 15;
  const int lk = lane >> 4;

  const int am0 = wm * 32 + l16;        // frag-0 output column (wo)
  const int am1 = wm * 32 + 16 + l16;   // frag-1

  // B global source: frag (f, ks) of tap t at
  //   bt[t*8192 + (wn*64 + f*16 + l16)*64 + ks*32 + lk*8]
  const unsigned short* bq_base = bt + (wn * 64 + l16) * 64 + lk * 8;

  f32x4 acc[2][4];
#pragma unroll
  for (int i = 0; i < 2; ++i)
#pragma unroll
    for (int j = 0; j < 4; ++j)
      acc[i][j] = (f32x4){0.f, 0.f, 0.f, 0.f};

#pragma unroll
  for (int kk = 0; kk < 9; ++kk) {
    const int kh = kk / 3;
    const int kw = kk - kh * 3;

    // A slab rows for this tap: pixel p = wo + kw, clamped (padded lanes
    // read valid duplicate data; their outputs are masked at the write).
    int p0 = am0 + kw; if (p0 > 111) p0 = 111;
    int p1 = am1 + kw; if (p1 > 111) p1 = 111;
    const unsigned short* ar0 = Asl + (kh * 112 + p0) * 64;
    const unsigned short* ar1 = Asl + (kh * 112 + p1) * 64;
    const int sz0 = (p0 & 7) << 4;
    const int sz1 = (p1 & 7) << 4;

    // B: 8 direct global loads (L1/L2-hit); no barrier, compiler pipelines
    const unsigned short* btap = bq_base + kk * 8192;
    bf16x8 b00 = *(const bf16x8*)(btap + 0 * 1024 + 0);
    bf16x8 b01 = *(const bf16x8*)(btap + 1 * 1024 + 0);
    bf16x8 b02 = *(const bf16x8*)(btap + 2 * 1024 + 0);
    bf16x8 b03 = *(const bf16x8*)(btap + 3 * 1024 + 0);
    bf16x8 b10 = *(const bf16x8*)(btap + 0 * 1024 + 32);
    bf16x8 b11 = *(const bf16x8*)(btap + 1 * 1024 + 32);
    bf16x8 b12 = *(const bf16x8*)(btap + 2 * 1024 + 32);
    bf16x8 b13 = *(const bf16x8*)(btap + 3 * 1024 + 32);

    // kstep 0 (k = 0..31)
    {
      const int kb = lk * 16;
      bf16x8 a0 = *(const bf16x8*)(ar0 + ((kb ^ sz0) >> 1));
      bf16x8 a1 = *(const bf16x8*)(ar1 + ((kb ^ sz1) >> 1));
      acc[0][0] = __builtin_amdgcn_mfma_f32_16x16x32_bf16(a0, b00, acc[0][0], 0, 0, 0);
      acc[0][1] = __builtin_amdgcn_mfma_f32_16x16x32_bf16(a0, b01, acc[0][1], 0, 0, 0);
      acc[0][2] = __builtin_amdgcn_mfma_f32_16x16x32_bf16(a0, b02, acc[0][2], 0, 0, 0);
      acc[0][3] = __builtin_amdgcn_mfma_f32_16x16x32_bf16(a0, b03, acc[0][3], 0, 0, 0);
      acc[1][0] = __builtin_amdgcn_mfma_f32_16x16x32_bf16(a1, b00, acc[1][0], 0, 0, 0);
      acc[1][1] = __builtin_amdgcn_mfma_f32_16x16x32_bf16(a1, b01, acc[1][1], 0, 0, 0);
      acc[1][2] = __builtin_amdgcn_mfma_f32_16x16x32_bf16(a1, b02, acc[1][2], 0, 0, 0);
      acc[1][3] = __builtin_amdgcn_mfma_f32_16x16x32_bf16(a1, b03, acc[1][3], 0, 0, 0);
    }
    // kstep 1 (k = 32..63)
    {
      const int kb = 64 + lk * 16;
      bf16x8 a0 = *(const bf16x8*)(ar0 + ((kb ^ sz0) >> 1));
      bf16x8 a1 = *(const bf16x8*)(ar1 + ((kb ^ sz1) >> 1));
      acc[0][0] = __builtin_amdgcn_mfma_f32_16x16x32_bf16(a0, b10, acc[0][0], 0, 0, 0);
      acc[0][1] = __builtin_amdgcn_mfma_f32_16x16x32_bf16(a0, b11, acc[0][1], 0, 0, 0);
      acc[0][2] = __builtin_amdgcn_mfma_f32_16x16x32_bf16(a0, b12, acc[0][2], 0, 0, 0);
      acc[0][3] = __builtin_amdgcn_mfma_f32_16x16x32_bf16(a0, b13, acc[0][3], 0, 0, 0);
      acc[1][0] = __builtin_amdgcn_mfma_f32_16x16x32_bf16(a1, b10, acc[1][0], 0, 0, 0);
      acc[1][1] = __builtin_amdgcn_mfma_f32_16x16x32_bf16(a1, b11, acc[1][1], 0, 0, 0);
      acc[1][2] = __builtin_amdgcn_mfma_f32_16x16x32_bf16(a1, b12, acc[1][2], 0, 0, 0);
      acc[1][3] = __builtin_amdgcn_mfma_f32_16x16x32_bf16(a1, b13, acc[1][3], 0, 0, 0);
    }
  }

  // ---- epilogue: bias + relu; C/D layout col=lane&15, row=(lane>>4)*4+reg.
  const int ncol = wn * 64 + l16;
  const float bv0 = bias[ncol + 0];
  const float bv1 = bias[ncol + 16];
  const float bv2 = bias[ncol + 32];
  const float bv3 = bias[ncol + 48];
  const size_t mbase = (size_t)bb * 12100 + (size_t)ho * 110;
#pragma unroll
  for (int mf = 0; mf < 2; ++mf) {
    const int wo0 = wm * 32 + mf * 16 + lk * 4;
#pragma unroll
    for (int j = 0; j < 4; ++j) {
      const int wo = wo0 + j;
      if (wo < 110) {
        float* orow = out + (mbase + wo) * COUT + ncol;
        orow[0]  = fmaxf(acc[mf][0][j] + bv0, 0.f);
        orow[16] = fmaxf(acc[mf][1][j] + bv1, 0.f);
        orow[32] = fmaxf(acc[mf][2][j] + bv2, 0.f);
        orow[48] = fmaxf(acc[mf][3][j] + bv3, 0.f);
      }
    }
  }
}

// ---- fallback (no workspace): R5's direct-staging kernel, known-correct.
__global__ __launch_bounds__(512)
void conv_fallback_kernel(const float* __restrict__ x,
                          const float* __restrict__ kern,
                          const float* __restrict__ bias,
                          float* __restrict__ out) {
  __shared__ __align__(16) unsigned short As[2][128 * 64];
  __shared__ __align__(16) unsigned short Bs[2][128 * 64];

  const int tid = threadIdx.x;
  const int m0 = blockIdx.x * 128;

  const int sr = tid >> 2;
  const int sc = tid & 3;
  const int m = m0 + sr;
  const int wo = m % WOUT;
  const int t1 = m / WOUT;
  const int ho = t1 % HOUT;
  const int b = t1 / HOUT;
  const float* xrow = x + (((b * IH) + ho) * IW + wo) * CIN + sc * 16;
  const int swzS = (sr & 7) << 4;
  const int awoff0 = sr * 64 + ((((sc * 32) + 0) ^ swzS) >> 1);
  const int awoff1 = sr * 64 + ((((sc * 32) + 16) ^ swzS) >> 1);

  const int bci = tid >> 3;
  const int bco = (tid & 7) * 16;

  const int lane = tid & 63;
  const int wid = tid >> 6;
  const int wm = wid >> 1;
  const int wn = wid & 1;
  const int l16 = lane & 15;
  const int lk = lane >> 4;
  const int swzR = (l16 & 7) << 4;

  const int aroff0 = (wm * 32 + 0 + l16) * 64;
  const int aroff1 = (wm * 32 + 16 + l16) * 64;
  const int broff0 = (wn * 64 + 0 + l16) * 64;
  const int broff1 = (wn * 64 + 16 + l16) * 64;
  const int broff2 = (wn * 64 + 32 + l16) * 64;
  const int broff3 = (wn * 64 + 48 + l16) * 64;

  f32x4 acc[2][4];
#pragma unroll
  for (int i = 0; i < 2; ++i)
#pragma unroll
    for (int j = 0; j < 4; ++j)
      acc[i][j] = (f32x4){0.f, 0.f, 0.f, 0.f};

  {
    f32x4 f0 = *(const f32x4*)(xrow + 0);
    f32x4 f1 = *(const f32x4*)(xrow + 4);
    f32x4 f2 = *(const f32x4*)(xrow + 8);
    f32x4 f3 = *(const f32x4*)(xrow + 12);
    u32x4 va, vb;
    va[0] = cvt2(f0[0], f0[1]); va[1] = cvt2(f0[2], f0[3]);
    va[2] = cvt2(f1[0], f1[1]); va[3] = cvt2(f1[2], f1[3]);
    vb[0] = cvt2(f2[0], f2[1]); vb[1] = cvt2(f2[2], f2[3]);
    vb[2] = cvt2(f3[0], f3[1]); vb[3] = cvt2(f3[2], f3[3]);
    *(u32x4*)(As[0] + awoff0) = va;
    *(u32x4*)(As[0] + awoff1) = vb;
    const float* kslab = kern + bci * COUT + bco;
    f32x4 g0 = *(const f32x4*)(kslab + 0);
    f32x4 g1 = *(const f32x4*)(kslab + 4);
    f32x4 g2 = *(const f32x4*)(kslab + 8);
    f32x4 g3 = *(const f32x4*)(kslab + 12);
#pragma unroll
    for (int j = 0; j < 4; ++j) {
      int c0 = bco + j;
      Bs[0][c0 * 64 + (((bci * 2) ^ ((c0 & 7) << 4)) >> 1)] = f2bf(g0[j]);
      int c1 = bco + 4 + j;
      Bs[0][c1 * 64 + (((bci * 2) ^ ((c1 & 7) << 4)) >> 1)] = f2bf(g1[j]);
      int c2 = bco + 8 + j;
      Bs[0][c2 * 64 + (((bci * 2) ^ ((c2 & 7) << 4)) >> 1)] = f2bf(g2[j]);
      int c3 = bco + 12 + j;
      Bs[0][c3 * 64 + (((bci * 2) ^ ((c3 & 7) << 4)) >> 1)] = f2bf(g3[j]);
    }
  }

#pragma unroll
  for (int kk = 0; kk < 9; ++kk) {
    const int cur = kk & 1;
    const int nxt = cur ^ 1;

    f32x4 g0, g1, g2, g3;
    f32x4 h0, h1, h2, h3;
    if (kk < 8) {
      const int kn = kk + 1;
      const int kh2 = kn / 3;
      const int kw2 = kn - kh2 * 3;
      const float* src = xrow + (kh2 * IW + kw2) * CIN;
      g0 = *(const f32x4*)(src + 0);
      g1 = *(const f32x4*)(src + 4);
      g2 = *(const f32x4*)(src + 8);
      g3 = *(const f32x4*)(src + 12);
      const float* kslab = kern + (kn * 64 + bci) * COUT + bco;
      h0 = *(const f32x4*)(kslab + 0);
      h1 = *(const f32x4*)(kslab + 4);
      h2 = *(const f32x4*)(kslab + 8);
      h3 = *(const f32x4*)(kslab + 12);
    }

    __syncthreads();

    const unsigned short* Ac = As[cur];
    const unsigned short* Bc = Bs[cur];
#pragma unroll
    for (int ks = 0; ks < 2; ++ks) {
      const int cbs = ((ks * 64 + lk * 16) ^ swzR) >> 1;
      bf16x8 a0 = *(const bf16x8*)(Ac + aroff0 + cbs);
      bf16x8 a1 = *(const bf16x8*)(Ac + aroff1 + cbs);
      bf16x8 b0 = *(const bf16x8*)(Bc + broff0 + cbs);
      bf16x8 b1 = *(const bf16x8*)(Bc + broff1 + cbs);
      bf16x8 b2 = *(const bf16x8*)(Bc + broff2 + cbs);
      bf16x8 b3 = *(const bf16x8*)(Bc + broff3 + cbs);
      acc[0][0] = __builtin_amdgcn_mfma_f32_16x16x32_bf16(a0, b0, acc[0][0], 0, 0, 0);
      acc[0][1] = __builtin_amdgcn_mfma_f32_16x16x32_bf16(a0, b1, acc[0][1], 0, 0, 0);
      acc[0][2] = __builtin_amdgcn_mfma_f32_16x16x32_bf16(a0, b2, acc[0][2], 0, 0, 0);
      acc[0][3] = __builtin_amdgcn_mfma_f32_16x16x32_bf16(a0, b3, acc[0][3], 0, 0, 0);
      acc[1][0] = __builtin_amdgcn_mfma_f32_16x16x32_bf16(a1, b0, acc[1][0], 0, 0, 0);
      acc[1][1] = __builtin_amdgcn_mfma_f32_16x16x32_bf16(a1, b1, acc[1][1], 0, 0, 0);
      acc[1][2] = __builtin_amdgcn_mfma_f32_16x16x32_bf16(a1, b2, acc[1][2], 0, 0, 0);
      acc[1][3] = __builtin_amdgcn_mfma_f32_16x16x32_bf16(a1, b3, acc[1][3], 0, 0, 0);
    }

    if (kk < 8) {
      u32x4 va, vb;
      va[0] = cvt2(g0[0], g0[1]); va[1] = cvt2(g0[2], g0[3]);
      va[2] = cvt2(g1[0], g1[1]); va[3] = cvt2(g1[2], g1[3]);
      vb[0] = cvt2(g2[0], g2[1]); vb[1] = cvt2(g2[2], g2[3]);
      vb[2] = cvt2(g3[0], g3[1]); vb[3] = cvt2(g3[2], g3[3]);
      *(u32x4*)(As[nxt] + awoff0) = va;
      *(u32x4*)(As[nxt] + awoff1) = vb;
#pragma unroll
      for (int j = 0; j < 4; ++j) {
        int c0 = bco + j;
        Bs[nxt][c0 * 64 + (((bci * 2) ^ ((c0 & 7) << 4)) >> 1)] = f2bf(h0[j]);
        int c1 = bco + 4 + j;
        Bs[nxt][c1 * 64 + (((bci * 2) ^ ((c1 & 7) << 4)) >> 1)] = f2bf(h1[j]);
        int c2 = bco + 8 + j;
        Bs[nxt][c2 * 64 + (((bci * 2) ^ ((c2 & 7) << 4)) >> 1)] = f2bf(h2[j]);
        int c3 = bco + 12 + j;
        Bs[nxt][c3 * 64 + (((bci * 2) ^ ((c3 & 7) << 4)) >> 1)] = f2bf(h3[j]);
      }
    }
  }

  const int ncol = wn * 64 + l16;
  const float bv0 = bias[ncol + 0];
  const float bv1 = bias[ncol + 16];
  const float bv2 = bias[ncol + 32];
  const float bv3 = bias[ncol + 48];
  const int mrow0 = m0 + wm * 32 + lk * 4;
#pragma unroll
  for (int mf = 0; mf < 2; ++mf) {
#pragma unroll
    for (int j = 0; j < 4; ++j) {
      const int row = mrow0 + mf * 16 + j;
      float* orow = out + (size_t)row * COUT + ncol;
      orow[0]  = fmaxf(acc[mf][0][j] + bv0, 0.f);
      orow[16] = fmaxf(acc[mf][1][j] + bv1, 0.f);
      orow[32] = fmaxf(acc[mf][2][j] + bv2, 0.f);
      orow[48] = fmaxf(acc[mf][3][j] + bv3, 0.f);
    }
  }
}

extern "C" void kernel_launch(void* const* d_in, const int* in_sizes, int n_in,
                              void* d_out, int out_size, void* d_ws, size_t ws_size,
                              hipStream_t stream) {
  const float* x = (const float*)d_in[0];
  const float* kern = (const float*)d_in[1];
  const float* bias = (const float*)d_in[2];
  float* out = (float*)d_out;

  const size_t bt_bytes = 9 * 8192 * 2;
  if (d_ws != nullptr && ws_size >= bt_bytes) {
    unsigned short* bt = (unsigned short*)d_ws;
    prepack_b_kernel<<<288, 256, 0, stream>>>(kern, bt);
    conv_fused_kernel<<<NWGF, 512, 0, stream>>>(x, bt, bias, out);
  } else {
    conv_fallback_kernel<<<3025, 512, 0, stream>>>(x, kern, bias, out);
  }
}

// Round 15
// 108.507 us; speedup vs baseline: 2.6241x; 2.6241x over previous
//
#include <hip/hip_runtime.h>
#include <hip/hip_bf16.h>

typedef __attribute__((ext_vector_type(4))) float f32x4;
typedef __attribute__((ext_vector_type(8))) short bf16x8;
typedef __attribute__((ext_vector_type(8))) unsigned short u16x8;
typedef __attribute__((ext_vector_type(4))) unsigned int u32x4;

#define HH 112
#define WW 112
#define CIN 64
#define COUT 128
#define HOUT 110
#define WOUT 110
#define MTOT 387200
#define NWG 3025   // 387200 / 128
#define NXCD 8
#define XNE 25690112  // 32*112*112*64 elements of x

__device__ __forceinline__ unsigned short f2bf(float f) {
  unsigned int x = __float_as_uint(f);
  x += 0x7fffu + ((x >> 16) & 1u);
  return (unsigned short)(x >> 16);
}

// packed fp32 pair -> bf16 pair (v_cvt_pk_bf16_f32)
__device__ __forceinline__ unsigned int cvt2(float lo, float hi) {
  union { __hip_bfloat162 h; unsigned int u; } cv;
  cv.h = __float22bfloat162_rn(float2{lo, hi});
  return cv.u;
}

// async global->LDS, 16B per lane; LDS dest is wave-uniform base + lane*16
__device__ __forceinline__ void gload16(const unsigned short* g, unsigned short* l) {
  __builtin_amdgcn_global_load_lds(
      (const __attribute__((address_space(1))) void*)g,
      (__attribute__((address_space(3))) void*)l, 16, 0, 0);
}

// ---- prepass: x fp32 -> bf16 (NHWC preserved), PLUS (merged) kernel prepack
// into the swizzled B LDS-image: bt[tap*8192 + co*64 + e], ci=((e*2)^((co&7)<<4))>>1.
// 12544 blocks x 256 thr x 8 elems == XNE exactly; first 73728 thread-slots
// additionally write one bt element (load imbalance negligible).
__global__ __launch_bounds__(256)
void cvt_x_kernel(const float* __restrict__ x, unsigned short* __restrict__ xb,
                  const float* __restrict__ kern, unsigned short* __restrict__ bt) {
  const int t = blockIdx.x * 256 + threadIdx.x;
  const f32x4* s = (const f32x4*)x + (size_t)t * 2;
  f32x4 a = s[0], b = s[1];
  u32x4 v;
  v[0] = cvt2(a[0], a[1]); v[1] = cvt2(a[2], a[3]);
  v[2] = cvt2(b[0], b[1]); v[3] = cvt2(b[2], b[3]);
  ((u32x4*)xb)[t] = v;
  if (t < 9 * 8192) {
    const int tap = t >> 13;
    const int rem = t & 8191;
    const int co = rem >> 6;
    const int e = rem & 63;
    const int ci = ((e * 2) ^ ((co & 7) << 4)) >> 1;
    bt[t] = f2bf(kern[(tap * 64 + ci) * COUT + co]);
  }
}

// ---- main: R12 chassis (proven 105.3 us): counted-vmcnt pipeline,
// A: 3 LDS buffers (2-deep), B: 2 buffers (1-deep), 80 KB -> 2 blk/CU,
// one raw s_barrier per tap, vmcnt never 0 in the loop.
// R15 delta: T5 s_setprio(1) around the MFMA cluster (wave role-diversity
// exists here via the pipeline + 2 blocks/CU).
__global__ __launch_bounds__(512, 4)
void conv_dma_kernel(const unsigned short* __restrict__ xb,
                     const unsigned short* __restrict__ bt,
                     const float* __restrict__ bias,
                     float* __restrict__ out) {
  __shared__ __align__(16) unsigned short As[3][8192];
  __shared__ __align__(16) unsigned short Bs[2][8192];

  const int tid = threadIdx.x;
  const int lane = tid & 63;
  const int wid = tid >> 6;

  // bijective XCD-chunked remap (m204); NWG=3025, q=378, r=1
  const int bid = blockIdx.x;
  const int q = NWG / NXCD, r = NWG % NXCD;
  const int xcd = bid % NXCD, i8 = bid / NXCD;
  const int wg = (xcd < r ? xcd * (q + 1) : r * (q + 1) + (xcd - r) * q) + i8;
  const int m0 = wg * 128;

  // ---- A staging (R8-verbatim): 2 DMA/thread/tap, pre-swizzled source.
  int aoff[2];
  const int obase = wid * 2048 + lane * 16;
#pragma unroll
  for (int j = 0; j < 2; ++j) {
    const int o = obase + j * 1024;
    const int rr = o >> 7;
    const int sp = ((o >> 4) & 7) ^ (rr & 7);
    const int m = m0 + rr;
    const int wo = m % WOUT;
    const int t1 = m / WOUT;
    const int ho = t1 % HOUT;
    const int bb = t1 / HOUT;
    aoff[j] = (((bb * HH) + ho) * WW + wo) * CIN + sp * 8;
  }
  const int ldsw0 = wid * 1024;
  const int ldsw1 = wid * 1024 + 512;
  const int blin0 = ldsw0 + lane * 8;  // B source (image pre-swizzled, linear copy)
  const int blin1 = ldsw1 + lane * 8;

  // ---- compute config: 8 waves = 4(m) x 2(n); wave tile 32x64 = 2x4 frags
  const int wm = wid >> 1;
  const int wn = wid & 1;
  const int l16 = lane & 15;
  const int lk = lane >> 4;
  const int swzR = (l16 & 7) << 4;

  const int aroff0 = (wm * 32 + 0 + l16) * 64;
  const int aroff1 = (wm * 32 + 16 + l16) * 64;
  const int broff0 = (wn * 64 + 0 + l16) * 64;
  const int broff1 = (wn * 64 + 16 + l16) * 64;
  const int broff2 = (wn * 64 + 32 + l16) * 64;
  const int broff3 = (wn * 64 + 48 + l16) * 64;

  f32x4 acc[2][4];
#pragma unroll
  for (int i = 0; i < 2; ++i)
#pragma unroll
    for (int j = 0; j < 4; ++j)
      acc[i][j] = (f32x4){0.f, 0.f, 0.f, 0.f};

  // tap -> x element offset (compile-time under full unroll)
  auto tapoff = [](int tap) {
    const int kh = tap / 3;
    const int kw = tap - kh * 3;
    return (kh * WW + kw) * CIN;
  };

  // ---- prologue. Issue order matters (FIFO retire): B(0), A(0), A(1).
  gload16(bt + blin0, &Bs[0][ldsw0]);
  gload16(bt + blin1, &Bs[0][ldsw1]);
  gload16(xb + aoff[0], &As[0][ldsw0]);
  gload16(xb + aoff[1], &As[0][ldsw1]);
  {
    const int te = tapoff(1);
    gload16(xb + aoff[0] + te, &As[1][ldsw0]);
    gload16(xb + aoff[1] + te, &As[1][ldsw1]);
  }

#pragma unroll
  for (int kk = 0; kk < 9; ++kk) {
    // counted wait: A(kk)+B(kk) landed; A(kk+1)'s 2 loads stay in flight.
    if (kk < 8) {
      asm volatile("s_waitcnt vmcnt(2)" ::: "memory");
    } else {
      asm volatile("s_waitcnt vmcnt(0)" ::: "memory");
    }
    __builtin_amdgcn_s_barrier();  // all waves: tap kk ready; buffers written
                                   // below were last read at iter kk-1 (done)

    // issue B(kk+1) FIRST, then A(kk+2) (so vmcnt(2) at iter kk+1 leaves
    // exactly A(kk+2) in flight and guarantees B(kk+1) landed).
    if (kk < 8) {
      const int tb = (kk + 1) * 8192;
      unsigned short* bd = Bs[(kk + 1) & 1];
      gload16(bt + tb + blin0, bd + ldsw0);
      gload16(bt + tb + blin1, bd + ldsw1);
    }
    if (kk < 7) {
      const int te = tapoff(kk + 2);
      unsigned short* ad = As[(kk + 2) % 3];
      gload16(xb + aoff[0] + te, ad + ldsw0);
      gload16(xb + aoff[1] + te, ad + ldsw1);
    }

    // ---- compute tap kk: 2 k-steps of 32, 8 MFMA each (R5/R8-proven pattern)
    // T5: boost priority through the MFMA cluster.
    const unsigned short* Ac = As[kk % 3];
    const unsigned short* Bc = Bs[kk & 1];
    __builtin_amdgcn_s_setprio(1);
#pragma unroll
    for (int ks = 0; ks < 2; ++ks) {
      const int cbs = ((ks * 64 + lk * 16) ^ swzR) >> 1;
      bf16x8 a0 = *(const bf16x8*)(Ac + aroff0 + cbs);
      bf16x8 a1 = *(const bf16x8*)(Ac + aroff1 + cbs);
      bf16x8 b0 = *(const bf16x8*)(Bc + broff0 + cbs);
      bf16x8 b1 = *(const bf16x8*)(Bc + broff1 + cbs);
      bf16x8 b2 = *(const bf16x8*)(Bc + broff2 + cbs);
      bf16x8 b3 = *(const bf16x8*)(Bc + broff3 + cbs);
      acc[0][0] = __builtin_amdgcn_mfma_f32_16x16x32_bf16(a0, b0, acc[0][0], 0, 0, 0);
      acc[0][1] = __builtin_amdgcn_mfma_f32_16x16x32_bf16(a0, b1, acc[0][1], 0, 0, 0);
      acc[0][2] = __builtin_amdgcn_mfma_f32_16x16x32_bf16(a0, b2, acc[0][2], 0, 0, 0);
      acc[0][3] = __builtin_amdgcn_mfma_f32_16x16x32_bf16(a0, b3, acc[0][3], 0, 0, 0);
      acc[1][0] = __builtin_amdgcn_mfma_f32_16x16x32_bf16(a1, b0, acc[1][0], 0, 0, 0);
      acc[1][1] = __builtin_amdgcn_mfma_f32_16x16x32_bf16(a1, b1, acc[1][1], 0, 0, 0);
      acc[1][2] = __builtin_amdgcn_mfma_f32_16x16x32_bf16(a1, b2, acc[1][2], 0, 0, 0);
      acc[1][3] = __builtin_amdgcn_mfma_f32_16x16x32_bf16(a1, b3, acc[1][3], 0, 0, 0);
    }
    __builtin_amdgcn_s_setprio(0);
  }

  // ---- epilogue: bias + relu, C/D layout col=lane&15, row=(lane>>4)*4+reg
  const int ncol = wn * 64 + l16;
  const float bv0 = bias[ncol + 0];
  const float bv1 = bias[ncol + 16];
  const float bv2 = bias[ncol + 32];
  const float bv3 = bias[ncol + 48];
  const int mrow0 = m0 + wm * 32 + lk * 4;
#pragma unroll
  for (int mf = 0; mf < 2; ++mf) {
#pragma unroll
    for (int j = 0; j < 4; ++j) {
      const int row = mrow0 + mf * 16 + j;
      float* orow = out + (size_t)row * COUT + ncol;
      orow[0]  = fmaxf(acc[mf][0][j] + bv0, 0.f);
      orow[16] = fmaxf(acc[mf][1][j] + bv1, 0.f);
      orow[32] = fmaxf(acc[mf][2][j] + bv2, 0.f);
      orow[48] = fmaxf(acc[mf][3][j] + bv3, 0.f);
    }
  }
}

// ---- fallback (no workspace): R5's direct-staging kernel, known-correct.
__global__ __launch_bounds__(512)
void conv_fallback_kernel(const float* __restrict__ x,
                          const float* __restrict__ kern,
                          const float* __restrict__ bias,
                          float* __restrict__ out) {
  __shared__ __align__(16) unsigned short As[2][128 * 64];
  __shared__ __align__(16) unsigned short Bs[2][128 * 64];

  const int tid = threadIdx.x;
  const int m0 = blockIdx.x * 128;

  const int sr = tid >> 2;
  const int sc = tid & 3;
  const int m = m0 + sr;
  const int wo = m % WOUT;
  const int t1 = m / WOUT;
  const int ho = t1 % HOUT;
  const int b = t1 / HOUT;
  const float* xrow = x + (((b * HH) + ho) * WW + wo) * CIN + sc * 16;
  const int swzS = (sr & 7) << 4;
  const int awoff0 = sr * 64 + ((((sc * 32) + 0) ^ swzS) >> 1);
  const int awoff1 = sr * 64 + ((((sc * 32) + 16) ^ swzS) >> 1);

  const int bci = tid >> 3;
  const int bco = (tid & 7) * 16;

  const int lane = tid & 63;
  const int wid = tid >> 6;
  const int wm = wid >> 1;
  const int wn = wid & 1;
  const int l16 = lane & 15;
  const int lk = lane >> 4;
  const int swzR = (l16 & 7) << 4;

  const int aroff0 = (wm * 32 + 0 + l16) * 64;
  const int aroff1 = (wm * 32 + 16 + l16) * 64;
  const int broff0 = (wn * 64 + 0 + l16) * 64;
  const int broff1 = (wn * 64 + 16 + l16) * 64;
  const int broff2 = (wn * 64 + 32 + l16) * 64;
  const int broff3 = (wn * 64 + 48 + l16) * 64;

  f32x4 acc[2][4];
#pragma unroll
  for (int i = 0; i < 2; ++i)
#pragma unroll
    for (int j = 0; j < 4; ++j)
      acc[i][j] = (f32x4){0.f, 0.f, 0.f, 0.f};

  {
    f32x4 f0 = *(const f32x4*)(xrow + 0);
    f32x4 f1 = *(const f32x4*)(xrow + 4);
    f32x4 f2 = *(const f32x4*)(xrow + 8);
    f32x4 f3 = *(const f32x4*)(xrow + 12);
    u32x4 va, vb;
    va[0] = cvt2(f0[0], f0[1]); va[1] = cvt2(f0[2], f0[3]);
    va[2] = cvt2(f1[0], f1[1]); va[3] = cvt2(f1[2], f1[3]);
    vb[0] = cvt2(f2[0], f2[1]); vb[1] = cvt2(f2[2], f2[3]);
    vb[2] = cvt2(f3[0], f3[1]); vb[3] = cvt2(f3[2], f3[3]);
    *(u32x4*)(As[0] + awoff0) = va;
    *(u32x4*)(As[0] + awoff1) = vb;
    const float* kslab = kern + bci * COUT + bco;
    f32x4 g0 = *(const f32x4*)(kslab + 0);
    f32x4 g1 = *(const f32x4*)(kslab + 4);
    f32x4 g2 = *(const f32x4*)(kslab + 8);
    f32x4 g3 = *(const f32x4*)(kslab + 12);
#pragma unroll
    for (int j = 0; j < 4; ++j) {
      int c0 = bco + j;
      Bs[0][c0 * 64 + (((bci * 2) ^ ((c0 & 7) << 4)) >> 1)] = f2bf(g0[j]);
      int c1 = bco + 4 + j;
      Bs[0][c1 * 64 + (((bci * 2) ^ ((c1 & 7) << 4)) >> 1)] = f2bf(g1[j]);
      int c2 = bco + 8 + j;
      Bs[0][c2 * 64 + (((bci * 2) ^ ((c2 & 7) << 4)) >> 1)] = f2bf(g2[j]);
      int c3 = bco + 12 + j;
      Bs[0][c3 * 64 + (((bci * 2) ^ ((c3 & 7) << 4)) >> 1)] = f2bf(g3[j]);
    }
  }

#pragma unroll
  for (int kk = 0; kk < 9; ++kk) {
    const int cur = kk & 1;
    const int nxt = cur ^ 1;

    f32x4 g0, g1, g2, g3;
    f32x4 h0, h1, h2, h3;
    if (kk < 8) {
      const int kn = kk + 1;
      const int kh2 = kn / 3;
      const int kw2 = kn - kh2 * 3;
      const float* src = xrow + (kh2 * WW + kw2) * CIN;
      g0 = *(const f32x4*)(src + 0);
      g1 = *(const f32x4*)(src + 4);
      g2 = *(const f32x4*)(src + 8);
      g3 = *(const f32x4*)(src + 12);
      const float* kslab = kern + (kn * 64 + bci) * COUT + bco;
      h0 = *(const f32x4*)(kslab + 0);
      h1 = *(const f32x4*)(kslab + 4);
      h2 = *(const f32x4*)(kslab + 8);
      h3 = *(const f32x4*)(kslab + 12);
    }

    __syncthreads();

    const unsigned short* Ac = As[cur];
    const unsigned short* Bc = Bs[cur];
#pragma unroll
    for (int ks = 0; ks < 2; ++ks) {
      const int cbs = ((ks * 64 + lk * 16) ^ swzR) >> 1;
      bf16x8 a0 = *(const bf16x8*)(Ac + aroff0 + cbs);
      bf16x8 a1 = *(const bf16x8*)(Ac + aroff1 + cbs);
      bf16x8 b0 = *(const bf16x8*)(Bc + broff0 + cbs);
      bf16x8 b1 = *(const bf16x8*)(Bc + broff1 + cbs);
      bf16x8 b2 = *(const bf16x8*)(Bc + broff2 + cbs);
      bf16x8 b3 = *(const bf16x8*)(Bc + broff3 + cbs);
      acc[0][0] = __builtin_amdgcn_mfma_f32_16x16x32_bf16(a0, b0, acc[0][0], 0, 0, 0);
      acc[0][1] = __builtin_amdgcn_mfma_f32_16x16x32_bf16(a0, b1, acc[0][1], 0, 0, 0);
      acc[0][2] = __builtin_amdgcn_mfma_f32_16x16x32_bf16(a0, b2, acc[0][2], 0, 0, 0);
      acc[0][3] = __builtin_amdgcn_mfma_f32_16x16x32_bf16(a0, b3, acc[0][3], 0, 0, 0);
      acc[1][0] = __builtin_amdgcn_mfma_f32_16x16x32_bf16(a1, b0, acc[1][0], 0, 0, 0);
      acc[1][1] = __builtin_amdgcn_mfma_f32_16x16x32_bf16(a1, b1, acc[1][1], 0, 0, 0);
      acc[1][2] = __builtin_amdgcn_mfma_f32_16x16x32_bf16(a1, b2, acc[1][2], 0, 0, 0);
      acc[1][3] = __builtin_amdgcn_mfma_f32_16x16x32_bf16(a1, b3, acc[1][3], 0, 0, 0);
    }

    if (kk < 8) {
      u32x4 va, vb;
      va[0] = cvt2(g0[0], g0[1]); va[1] = cvt2(g0[2], g0[3]);
      va[2] = cvt2(g1[0], g1[1]); va[3] = cvt2(g1[2], g1[3]);
      vb[0] = cvt2(g2[0], g2[1]); vb[1] = cvt2(g2[2], g2[3]);
      vb[2] = cvt2(g3[0], g3[1]); vb[3] = cvt2(g3[2], g3[3]);
      *(u32x4*)(As[nxt] + awoff0) = va;
      *(u32x4*)(As[nxt] + awoff1) = vb;
#pragma unroll
      for (int j = 0; j < 4; ++j) {
        int c0 = bco + j;
        Bs[nxt][c0 * 64 + (((bci * 2) ^ ((c0 & 7) << 4)) >> 1)] = f2bf(h0[j]);
        int c1 = bco + 4 + j;
        Bs[nxt][c1 * 64 + (((bci * 2) ^ ((c1 & 7) << 4)) >> 1)] = f2bf(h1[j]);
        int c2 = bco + 8 + j;
        Bs[nxt][c2 * 64 + (((bci * 2) ^ ((c2 & 7) << 4)) >> 1)] = f2bf(h2[j]);
        int c3 = bco + 12 + j;
        Bs[nxt][c3 * 64 + (((bci * 2) ^ ((c3 & 7) << 4)) >> 1)] = f2bf(h3[j]);
      }
    }
  }

  const int ncol = wn * 64 + l16;
  const float bv0 = bias[ncol + 0];
  const float bv1 = bias[ncol + 16];
  const float bv2 = bias[ncol + 32];
  const float bv3 = bias[ncol + 48];
  const int mrow0 = m0 + wm * 32 + lk * 4;
#pragma unroll
  for (int mf = 0; mf < 2; ++mf) {
#pragma unroll
    for (int j = 0; j < 4; ++j) {
      const int row = mrow0 + mf * 16 + j;
      float* orow = out + (size_t)row * COUT + ncol;
      orow[0]  = fmaxf(acc[mf][0][j] + bv0, 0.f);
      orow[16] = fmaxf(acc[mf][1][j] + bv1, 0.f);
      orow[32] = fmaxf(acc[mf][2][j] + bv2, 0.f);
      orow[48] = fmaxf(acc[mf][3][j] + bv3, 0.f);
    }
  }
}

extern "C" void kernel_launch(void* const* d_in, const int* in_sizes, int n_in,
                              void* d_out, int out_size, void* d_ws, size_t ws_size,
                              hipStream_t stream) {
  const float* x = (const float*)d_in[0];
  const float* kern = (const float*)d_in[1];
  const float* bias = (const float*)d_in[2];
  float* out = (float*)d_out;

  const size_t xb_bytes = (size_t)XNE * 2;
  const size_t bt_bytes = 9 * 8192 * 2;
  if (d_ws != nullptr && ws_size >= xb_bytes + bt_bytes) {
    unsigned short* xb = (unsigned short*)d_ws;
    unsigned short* bt = xb + XNE;
    cvt_x_kernel<<<12544, 256, 0, stream>>>(x, xb, kern, bt);
    conv_dma_kernel<<<NWG, 512, 0, stream>>>(xb, bt, bias, out);
  } else {
    conv_fallback_kernel<<<3025, 512, 0, stream>>>(x, kern, bias, out);
  }
}

// Round 16
// 103.114 us; speedup vs baseline: 2.7613x; 1.0523x over previous
//
#include <hip/hip_runtime.h>
#include <hip/hip_bf16.h>

typedef __attribute__((ext_vector_type(4))) float f32x4;
typedef __attribute__((ext_vector_type(8))) short bf16x8;
typedef __attribute__((ext_vector_type(8))) unsigned short u16x8;
typedef __attribute__((ext_vector_type(4))) unsigned int u32x4;

#define HH 112
#define WW 112
#define CIN 64
#define COUT 128
#define HOUT 110
#define WOUT 110
#define MTOT 387200
#define NWG 3025   // 387200 / 128, exact
#define NXCD 8
#define XNE 25690112  // 32*112*112*64 elements of x

__device__ __forceinline__ unsigned short f2bf(float f) {
  unsigned int x = __float_as_uint(f);
  x += 0x7fffu + ((x >> 16) & 1u);
  return (unsigned short)(x >> 16);
}

// packed fp32 pair -> bf16 pair (v_cvt_pk_bf16_f32)
__device__ __forceinline__ unsigned int cvt2(float lo, float hi) {
  union { __hip_bfloat162 h; unsigned int u; } cv;
  cv.h = __float22bfloat162_rn(float2{lo, hi});
  return cv.u;
}

// async global->LDS, 16B per lane; LDS dest is wave-uniform base + lane*16
__device__ __forceinline__ void gload16(const unsigned short* g, unsigned short* l) {
  __builtin_amdgcn_global_load_lds(
      (const __attribute__((address_space(1))) void*)g,
      (__attribute__((address_space(3))) void*)l, 16, 0, 0);
}

// ---- prepass: x fp32 -> bf16 (NHWC preserved). R12-exact (merge reverted).
__global__ __launch_bounds__(256)
void cvt_x_kernel(const float* __restrict__ x, unsigned short* __restrict__ xb) {
  const int t = blockIdx.x * 256 + threadIdx.x;
  const f32x4* s = (const f32x4*)x + (size_t)t * 2;
  f32x4 a = s[0], b = s[1];
  u32x4 v;
  v[0] = cvt2(a[0], a[1]); v[1] = cvt2(a[2], a[3]);
  v[2] = cvt2(b[0], b[1]); v[3] = cvt2(b[2], b[3]);
  ((u32x4*)xb)[t] = v;
}

// ---- prepack kernels (3,3,64,128) fp32 HWIO -> swizzled LDS image (R12-exact)
__global__ void prepack_b_kernel(const float* __restrict__ kern,
                                 unsigned short* __restrict__ bt) {
  int idx = blockIdx.x * 256 + threadIdx.x;
  if (idx >= 9 * 8192) return;
  int tap = idx >> 13;
  int rem = idx & 8191;
  int co = rem >> 6;
  int e = rem & 63;
  int ci = ((e * 2) ^ ((co & 7) << 4)) >> 1;
  bt[idx] = f2bf(kern[(tap * 64 + ci) * COUT + co]);
}

// ---- main: R12 counted-vmcnt pipeline (3 A-buffers, 2 B-buffers, 80 KB,
// 2 blocks/CU) at NEW geometry: 256 threads, 4 waves of 64x64 wave tiles
// (reads/MFMA 0.75 -> 0.5, LDS traffic -33%). vmcnt counts scaled to
// 4 loads/tensor/tap (trace in comments).
__global__ __launch_bounds__(256, 2)
void conv_dma_kernel(const unsigned short* __restrict__ xb,
                     const unsigned short* __restrict__ bt,
                     const float* __restrict__ bias,
                     float* __restrict__ out) {
  __shared__ __align__(16) unsigned short As[3][8192];
  __shared__ __align__(16) unsigned short Bs[2][8192];

  const int tid = threadIdx.x;
  const int lane = tid & 63;
  const int wid = tid >> 6;  // 0..3

  // bijective XCD-chunked remap (m204); NWG=3025, q=378, r=1
  const int bid = blockIdx.x;
  const int q = NWG / NXCD, r = NWG % NXCD;
  const int xcd = bid % NXCD, i8 = bid / NXCD;
  const int wg = (xcd < r ? xcd * (q + 1) : r * (q + 1) + (xcd - r) * q) + i8;
  const int m0 = wg * 128;

  // ---- A staging: 4 DMA/thread/tap. Dest byte o = j*4096 + tid*16
  // (wave-uniform base + lane*16). Image row rr = o>>7 (128B rows),
  // slot (o>>4)&7 holds global chunk slot^(rr&7) [pre-swizzled source].
  int aoff[4];
#pragma unroll
  for (int j = 0; j < 4; ++j) {
    const int o = j * 4096 + tid * 16;
    const int rr = o >> 7;
    const int sp = ((o >> 4) & 7) ^ (rr & 7);
    const int m = m0 + rr;
    const int wo = m % WOUT;
    const int t1 = m / WOUT;
    const int ho = t1 % HOUT;
    const int bb = t1 / HOUT;
    aoff[j] = (((bb * HH) + ho) * WW + wo) * CIN + sp * 8;
  }
  // wave-uniform LDS element bases; B per-lane pre-swizzled-image sources
  int ldsw[4], blin[4];
#pragma unroll
  for (int j = 0; j < 4; ++j) {
    ldsw[j] = j * 2048 + wid * 512;
    blin[j] = ldsw[j] + lane * 8;
  }

  // ---- compute config: 4 waves = 2(m) x 2(n); wave tile 64x64 = 4x4 frags
  const int wm = wid >> 1;
  const int wn = wid & 1;
  const int l16 = lane & 15;
  const int lk = lane >> 4;
  const int swzR = (l16 & 7) << 4;

  int ar[4], br[4];
#pragma unroll
  for (int f = 0; f < 4; ++f) {
    ar[f] = (wm * 64 + f * 16 + l16) * 64;
    br[f] = (wn * 64 + f * 16 + l16) * 64;
  }

  f32x4 acc[4][4];
#pragma unroll
  for (int i = 0; i < 4; ++i)
#pragma unroll
    for (int j = 0; j < 4; ++j)
      acc[i][j] = (f32x4){0.f, 0.f, 0.f, 0.f};

  // tap -> x element offset (compile-time under full unroll)
  auto tapoff = [](int tap) {
    const int kh = tap / 3;
    const int kw = tap - kh * 3;
    return (kh * WW + kw) * CIN;
  };

  // ---- prologue. FIFO issue order: B(0)x4, A(0)x4, A(1)x4 = 12 outstanding.
  // Iter-kk invariant (kk<8): top-of-loop outstanding = A(kk),B(kk),A(kk+1)
  // (12); vmcnt(4) drains A(kk)+B(kk), leaves A(kk+1) in flight.
#pragma unroll
  for (int j = 0; j < 4; ++j) gload16(bt + blin[j], &Bs[0][ldsw[j]]);
#pragma unroll
  for (int j = 0; j < 4; ++j) gload16(xb + aoff[j], &As[0][ldsw[j]]);
  {
    const int te = tapoff(1);
#pragma unroll
    for (int j = 0; j < 4; ++j) gload16(xb + aoff[j] + te, &As[1][ldsw[j]]);
  }

#pragma unroll
  for (int kk = 0; kk < 9; ++kk) {
    // counted wait: A(kk)+B(kk) landed; A(kk+1)'s 4 loads stay in flight.
    if (kk < 8) {
      asm volatile("s_waitcnt vmcnt(4)" ::: "memory");
    } else {
      asm volatile("s_waitcnt vmcnt(0)" ::: "memory");
    }
    __builtin_amdgcn_s_barrier();  // all waves: tap kk ready; buffers written
                                   // below were last read at iter kk-1

    // issue B(kk+1) FIRST, then A(kk+2) (FIFO: next iter's vmcnt(4) then
    // drains exactly A(kk+1)+B(kk+1), leaving A(kk+2) in flight).
    if (kk < 8) {
      const int tb = (kk + 1) * 8192;
      unsigned short* bd = Bs[(kk + 1) & 1];
#pragma unroll
      for (int j = 0; j < 4; ++j) gload16(bt + tb + blin[j], bd + ldsw[j]);
    }
    if (kk < 7) {
      const int te = tapoff(kk + 2);
      unsigned short* ad = As[(kk + 2) % 3];
#pragma unroll
      for (int j = 0; j < 4; ++j) gload16(xb + aoff[j] + te, ad + ldsw[j]);
    }

    // ---- compute tap kk: 2 k-steps of 32, 16 MFMA each (R9-proven body)
    const unsigned short* Ac = As[kk % 3];
    const unsigned short* Bc = Bs[kk & 1];
#pragma unroll
    for (int ks = 0; ks < 2; ++ks) {
      const int cbs = ((ks * 64 + lk * 16) ^ swzR) >> 1;
      bf16x8 a0 = *(const bf16x8*)(Ac + ar[0] + cbs);
      bf16x8 a1 = *(const bf16x8*)(Ac + ar[1] + cbs);
      bf16x8 a2 = *(const bf16x8*)(Ac + ar[2] + cbs);
      bf16x8 a3 = *(const bf16x8*)(Ac + ar[3] + cbs);
      bf16x8 b0 = *(const bf16x8*)(Bc + br[0] + cbs);
      bf16x8 b1 = *(const bf16x8*)(Bc + br[1] + cbs);
      bf16x8 b2 = *(const bf16x8*)(Bc + br[2] + cbs);
      bf16x8 b3 = *(const bf16x8*)(Bc + br[3] + cbs);
      acc[0][0] = __builtin_amdgcn_mfma_f32_16x16x32_bf16(a0, b0, acc[0][0], 0, 0, 0);
      acc[0][1] = __builtin_amdgcn_mfma_f32_16x16x32_bf16(a0, b1, acc[0][1], 0, 0, 0);
      acc[0][2] = __builtin_amdgcn_mfma_f32_16x16x32_bf16(a0, b2, acc[0][2], 0, 0, 0);
      acc[0][3] = __builtin_amdgcn_mfma_f32_16x16x32_bf16(a0, b3, acc[0][3], 0, 0, 0);
      acc[1][0] = __builtin_amdgcn_mfma_f32_16x16x32_bf16(a1, b0, acc[1][0], 0, 0, 0);
      acc[1][1] = __builtin_amdgcn_mfma_f32_16x16x32_bf16(a1, b1, acc[1][1], 0, 0, 0);
      acc[1][2] = __builtin_amdgcn_mfma_f32_16x16x32_bf16(a1, b2, acc[1][2], 0, 0, 0);
      acc[1][3] = __builtin_amdgcn_mfma_f32_16x16x32_bf16(a1, b3, acc[1][3], 0, 0, 0);
      acc[2][0] = __builtin_amdgcn_mfma_f32_16x16x32_bf16(a2, b0, acc[2][0], 0, 0, 0);
      acc[2][1] = __builtin_amdgcn_mfma_f32_16x16x32_bf16(a2, b1, acc[2][1], 0, 0, 0);
      acc[2][2] = __builtin_amdgcn_mfma_f32_16x16x32_bf16(a2, b2, acc[2][2], 0, 0, 0);
      acc[2][3] = __builtin_amdgcn_mfma_f32_16x16x32_bf16(a2, b3, acc[2][3], 0, 0, 0);
      acc[3][0] = __builtin_amdgcn_mfma_f32_16x16x32_bf16(a3, b0, acc[3][0], 0, 0, 0);
      acc[3][1] = __builtin_amdgcn_mfma_f32_16x16x32_bf16(a3, b1, acc[3][1], 0, 0, 0);
      acc[3][2] = __builtin_amdgcn_mfma_f32_16x16x32_bf16(a3, b2, acc[3][2], 0, 0, 0);
      acc[3][3] = __builtin_amdgcn_mfma_f32_16x16x32_bf16(a3, b3, acc[3][3], 0, 0, 0);
    }
  }

  // ---- epilogue: bias + relu, C/D layout col=lane&15, row=(lane>>4)*4+reg
  const int ncol = wn * 64 + l16;
  const float bv0 = bias[ncol + 0];
  const float bv1 = bias[ncol + 16];
  const float bv2 = bias[ncol + 32];
  const float bv3 = bias[ncol + 48];
#pragma unroll
  for (int mf = 0; mf < 4; ++mf) {
    const int rbase = m0 + wm * 64 + mf * 16 + lk * 4;
#pragma unroll
    for (int j = 0; j < 4; ++j) {
      float* orow = out + (size_t)(rbase + j) * COUT + ncol;
      orow[0]  = fmaxf(acc[mf][0][j] + bv0, 0.f);
      orow[16] = fmaxf(acc[mf][1][j] + bv1, 0.f);
      orow[32] = fmaxf(acc[mf][2][j] + bv2, 0.f);
      orow[48] = fmaxf(acc[mf][3][j] + bv3, 0.f);
    }
  }
}

// ---- fallback (no workspace): R5's direct-staging kernel, known-correct.
__global__ __launch_bounds__(512)
void conv_fallback_kernel(const float* __restrict__ x,
                          const float* __restrict__ kern,
                          const float* __restrict__ bias,
                          float* __restrict__ out) {
  __shared__ __align__(16) unsigned short As[2][128 * 64];
  __shared__ __align__(16) unsigned short Bs[2][128 * 64];

  const int tid = threadIdx.x;
  const int m0 = blockIdx.x * 128;

  const int sr = tid >> 2;
  const int sc = tid & 3;
  const int m = m0 + sr;
  const int wo = m % WOUT;
  const int t1 = m / WOUT;
  const int ho = t1 % HOUT;
  const int b = t1 / HOUT;
  const float* xrow = x + (((b * HH) + ho) * WW + wo) * CIN + sc * 16;
  const int swzS = (sr & 7) << 4;
  const int awoff0 = sr * 64 + ((((sc * 32) + 0) ^ swzS) >> 1);
  const int awoff1 = sr * 64 + ((((sc * 32) + 16) ^ swzS) >> 1);

  const int bci = tid >> 3;
  const int bco = (tid & 7) * 16;

  const int lane = tid & 63;
  const int wid = tid >> 6;
  const int wm = wid >> 1;
  const int wn = wid & 1;
  const int l16 = lane & 15;
  const int lk = lane >> 4;
  const int swzR = (l16 & 7) << 4;

  const int aroff0 = (wm * 32 + 0 + l16) * 64;
  const int aroff1 = (wm * 32 + 16 + l16) * 64;
  const int broff0 = (wn * 64 + 0 + l16) * 64;
  const int broff1 = (wn * 64 + 16 + l16) * 64;
  const int broff2 = (wn * 64 + 32 + l16) * 64;
  const int broff3 = (wn * 64 + 48 + l16) * 64;

  f32x4 acc[2][4];
#pragma unroll
  for (int i = 0; i < 2; ++i)
#pragma unroll
    for (int j = 0; j < 4; ++j)
      acc[i][j] = (f32x4){0.f, 0.f, 0.f, 0.f};

  {
    f32x4 f0 = *(const f32x4*)(xrow + 0);
    f32x4 f1 = *(const f32x4*)(xrow + 4);
    f32x4 f2 = *(const f32x4*)(xrow + 8);
    f32x4 f3 = *(const f32x4*)(xrow + 12);
    u32x4 va, vb;
    va[0] = cvt2(f0[0], f0[1]); va[1] = cvt2(f0[2], f0[3]);
    va[2] = cvt2(f1[0], f1[1]); va[3] = cvt2(f1[2], f1[3]);
    vb[0] = cvt2(f2[0], f2[1]); vb[1] = cvt2(f2[2], f2[3]);
    vb[2] = cvt2(f3[0], f3[1]); vb[3] = cvt2(f3[2], f3[3]);
    *(u32x4*)(As[0] + awoff0) = va;
    *(u32x4*)(As[0] + awoff1) = vb;
    const float* kslab = kern + bci * COUT + bco;
    f32x4 g0 = *(const f32x4*)(kslab + 0);
    f32x4 g1 = *(const f32x4*)(kslab + 4);
    f32x4 g2 = *(const f32x4*)(kslab + 8);
    f32x4 g3 = *(const f32x4*)(kslab + 12);
#pragma unroll
    for (int j = 0; j < 4; ++j) {
      int c0 = bco + j;
      Bs[0][c0 * 64 + (((bci * 2) ^ ((c0 & 7) << 4)) >> 1)] = f2bf(g0[j]);
      int c1 = bco + 4 + j;
      Bs[0][c1 * 64 + (((bci * 2) ^ ((c1 & 7) << 4)) >> 1)] = f2bf(g1[j]);
      int c2 = bco + 8 + j;
      Bs[0][c2 * 64 + (((bci * 2) ^ ((c2 & 7) << 4)) >> 1)] = f2bf(g2[j]);
      int c3 = bco + 12 + j;
      Bs[0][c3 * 64 + (((bci * 2) ^ ((c3 & 7) << 4)) >> 1)] = f2bf(g3[j]);
    }
  }

#pragma unroll
  for (int kk = 0; kk < 9; ++kk) {
    const int cur = kk & 1;
    const int nxt = cur ^ 1;

    f32x4 g0, g1, g2, g3;
    f32x4 h0, h1, h2, h3;
    if (kk < 8) {
      const int kn = kk + 1;
      const int kh2 = kn / 3;
      const int kw2 = kn - kh2 * 3;
      const float* src = xrow + (kh2 * WW + kw2) * CIN;
      g0 = *(const f32x4*)(src + 0);
      g1 = *(const f32x4*)(src + 4);
      g2 = *(const f32x4*)(src + 8);
      g3 = *(const f32x4*)(src + 12);
      const float* kslab = kern + (kn * 64 + bci) * COUT + bco;
      h0 = *(const f32x4*)(kslab + 0);
      h1 = *(const f32x4*)(kslab + 4);
      h2 = *(const f32x4*)(kslab + 8);
      h3 = *(const f32x4*)(kslab + 12);
    }

    __syncthreads();

    const unsigned short* Ac = As[cur];
    const unsigned short* Bc = Bs[cur];
#pragma unroll
    for (int ks = 0; ks < 2; ++ks) {
      const int cbs = ((ks * 64 + lk * 16) ^ swzR) >> 1;
      bf16x8 a0 = *(const bf16x8*)(Ac + aroff0 + cbs);
      bf16x8 a1 = *(const bf16x8*)(Ac + aroff1 + cbs);
      bf16x8 b0 = *(const bf16x8*)(Bc + broff0 + cbs);
      bf16x8 b1 = *(const bf16x8*)(Bc + broff1 + cbs);
      bf16x8 b2 = *(const bf16x8*)(Bc + broff2 + cbs);
      bf16x8 b3 = *(const bf16x8*)(Bc + broff3 + cbs);
      acc[0][0] = __builtin_amdgcn_mfma_f32_16x16x32_bf16(a0, b0, acc[0][0], 0, 0, 0);
      acc[0][1] = __builtin_amdgcn_mfma_f32_16x16x32_bf16(a0, b1, acc[0][1], 0, 0, 0);
      acc[0][2] = __builtin_amdgcn_mfma_f32_16x16x32_bf16(a0, b2, acc[0][2], 0, 0, 0);
      acc[0][3] = __builtin_amdgcn_mfma_f32_16x16x32_bf16(a0, b3, acc[0][3], 0, 0, 0);
      acc[1][0] = __builtin_amdgcn_mfma_f32_16x16x32_bf16(a1, b0, acc[1][0], 0, 0, 0);
      acc[1][1] = __builtin_amdgcn_mfma_f32_16x16x32_bf16(a1, b1, acc[1][1], 0, 0, 0);
      acc[1][2] = __builtin_amdgcn_mfma_f32_16x16x32_bf16(a1, b2, acc[1][2], 0, 0, 0);
      acc[1][3] = __builtin_amdgcn_mfma_f32_16x16x32_bf16(a1, b3, acc[1][3], 0, 0, 0);
    }

    if (kk < 8) {
      u32x4 va, vb;
      va[0] = cvt2(g0[0], g0[1]); va[1] = cvt2(g0[2], g0[3]);
      va[2] = cvt2(g1[0], g1[1]); va[3] = cvt2(g1[2], g1[3]);
      vb[0] = cvt2(g2[0], g2[1]); vb[1] = cvt2(g2[2], g2[3]);
      vb[2] = cvt2(g3[0], g3[1]); vb[3] = cvt2(g3[2], g3[3]);
      *(u32x4*)(As[nxt] + awoff0) = va;
      *(u32x4*)(As[nxt] + awoff1) = vb;
#pragma unroll
      for (int j = 0; j < 4; ++j) {
        int c0 = bco + j;
        Bs[nxt][c0 * 64 + (((bci * 2) ^ ((c0 & 7) << 4)) >> 1)] = f2bf(h0[j]);
        int c1 = bco + 4 + j;
        Bs[nxt][c1 * 64 + (((bci * 2) ^ ((c1 & 7) << 4)) >> 1)] = f2bf(h1[j]);
        int c2 = bco + 8 + j;
        Bs[nxt][c2 * 64 + (((bci * 2) ^ ((c2 & 7) << 4)) >> 1)] = f2bf(h2[j]);
        int c3 = bco + 12 + j;
        Bs[nxt][c3 * 64 + (((bci * 2) ^ ((c3 & 7) << 4)) >> 1)] = f2bf(h3[j]);
      }
    }
  }

  const int ncol = wn * 64 + l16;
  const float bv0 = bias[ncol + 0];
  const float bv1 = bias[ncol + 16];
  const float bv2 = bias[ncol + 32];
  const float bv3 = bias[ncol + 48];
  const int mrow0 = m0 + wm * 32 + lk * 4;
#pragma unroll
  for (int mf = 0; mf < 2; ++mf) {
#pragma unroll
    for (int j = 0; j < 4; ++j) {
      const int row = mrow0 + mf * 16 + j;
      float* orow = out + (size_t)row * COUT + ncol;
      orow[0]  = fmaxf(acc[mf][0][j] + bv0, 0.f);
      orow[16] = fmaxf(acc[mf][1][j] + bv1, 0.f);
      orow[32] = fmaxf(acc[mf][2][j] + bv2, 0.f);
      orow[48] = fmaxf(acc[mf][3][j] + bv3, 0.f);
    }
  }
}

extern "C" void kernel_launch(void* const* d_in, const int* in_sizes, int n_in,
                              void* d_out, int out_size, void* d_ws, size_t ws_size,
                              hipStream_t stream) {
  const float* x = (const float*)d_in[0];
  const float* kern = (const float*)d_in[1];
  const float* bias = (const float*)d_in[2];
  float* out = (float*)d_out;

  const size_t xb_bytes = (size_t)XNE * 2;
  const size_t bt_bytes = 9 * 8192 * 2;
  if (d_ws != nullptr && ws_size >= xb_bytes + bt_bytes) {
    unsigned short* xb = (unsigned short*)d_ws;
    unsigned short* bt = xb + XNE;
    cvt_x_kernel<<<12544, 256, 0, stream>>>(x, xb);
    prepack_b_kernel<<<288, 256, 0, stream>>>(kern, bt);
    conv_dma_kernel<<<NWG, 256, 0, stream>>>(xb, bt, bias, out);
  } else {
    conv_fallback_kernel<<<3025, 512, 0, stream>>>(x, kern, bias, out);
  }
}